// Round 9
// baseline (279.296 us; speedup 1.0000x reference)
//
#include <hip/hip_runtime.h>
#include <hip/hip_fp16.h>

#define FIN 128
#define HID 32
#define BSHIFT 8                 // 256 nodes per coarse bucket
#define BNODES 256
#define CHUNK 2048               // edges per chunk-sort block
#define NBMAX 512                // max coarse buckets supported in LDS
#define CAPB 8960                // max entries per bucket (mean 8184, +8.6 sigma)
#define G1ROWS 64                // rows per gemm block

// ---------------- A: per-chunk counting sort by bucket (all I/O coalesced) ----------------

__global__ __launch_bounds__(256) void chunk_sort_kernel(const int* __restrict__ src,
                                                         const int* __restrict__ dst,
                                                         int* __restrict__ ec,
                                                         unsigned short* __restrict__ offt,
                                                         int E, int nb) {
    __shared__ int hist[NBMAX];
    __shared__ int pref[NBMAX];
    __shared__ int sorted[CHUNK];
    int c = blockIdx.x, t = threadIdx.x;
    int beg = c * CHUNK;
    int cnt = min(CHUNK, E - beg);
    for (int i = t; i < nb; i += 256) hist[i] = 0;
    __syncthreads();
    int bk[8], ent[8];
    #pragma unroll
    for (int j = 0; j < 8; ++j) {
        int i = t + j * 256;
        if (i < cnt) {
            int d = dst[beg + i];
            bk[j]  = ((unsigned)d) >> BSHIFT;
            ent[j] = src[beg + i] | ((d & (BNODES - 1)) << 24);
            atomicAdd(&hist[bk[j]], 1);
        } else bk[j] = -1;
    }
    __syncthreads();
    // single-wave exclusive scan over nb (<= NBMAX = 64 lanes * 8) buckets
    if (t < 64) {
        int v[8];
        int s = 0;
        #pragma unroll
        for (int j = 0; j < 8; ++j) {
            int idx = t * 8 + j;
            int h = (idx < nb) ? hist[idx] : 0;
            v[j] = s; s += h;
        }
        int run = s;
        #pragma unroll
        for (int d = 1; d < 64; d <<= 1) {
            int o = __shfl_up(run, d, 64);
            if (t >= d) run += o;
        }
        int excl = run - s;
        #pragma unroll
        for (int j = 0; j < 8; ++j) {
            int idx = t * 8 + j;
            if (idx < nb) { int p = excl + v[j]; pref[idx] = p; hist[idx] = p; }
        }
    }
    __syncthreads();
    #pragma unroll
    for (int j = 0; j < 8; ++j) {
        if (bk[j] >= 0) {
            int p = atomicAdd(&hist[bk[j]], 1);
            sorted[p] = ent[j];
        }
    }
    __syncthreads();
    for (int i = t; i < cnt; i += 256) ec[(size_t)c * CHUNK + i] = sorted[i];   // coalesced
    unsigned short* row = offt + (size_t)c * (nb + 1);
    for (int i = t; i < nb; i += 256) row[i] = (unsigned short)pref[i];
    if (t == 0) row[nb] = (unsigned short)cnt;
}

// ---------------- B: per-bucket gather of chunk runs + node counting sort ----------------

__global__ __launch_bounds__(1024) void bucket_build_kernel(const int* __restrict__ ec,
                                                            const unsigned short* __restrict__ offt,
                                                            int* __restrict__ entries,
                                                            float* __restrict__ dinv,
                                                            int* __restrict__ rowbeg,
                                                            int* __restrict__ rowcnt,
                                                            int n, int nb, int nchunks, int cap) {
    __shared__ int raw[CAPB];
    __shared__ int srt[CAPB];
    __shared__ int hist[BNODES];
    __shared__ int pref[BNODES];
    __shared__ int cursor[BNODES];
    __shared__ int nfill;
    int b = blockIdx.x, t = threadIdx.x;
    if (t < BNODES) hist[t] = 0;
    if (t == 0) nfill = 0;
    __syncthreads();
    for (int c = t; c < nchunks; c += 1024) {
        const unsigned short* row = offt + (size_t)c * (nb + 1);
        int s = row[b], e2 = row[b + 1];
        int m = e2 - s;
        if (m > 0) {
            int base = atomicAdd(&nfill, m);
            const int* p = ec + (size_t)c * CHUNK + s;
            int k = 0;
            for (; k + 4 <= m; k += 4) {           // 4 independent loads in flight
                int e0 = p[k], e1 = p[k + 1], e2v = p[k + 2], e3 = p[k + 3];
                if (base + k + 0 < CAPB) raw[base + k + 0] = e0;
                if (base + k + 1 < CAPB) raw[base + k + 1] = e1;
                if (base + k + 2 < CAPB) raw[base + k + 2] = e2v;
                if (base + k + 3 < CAPB) raw[base + k + 3] = e3;
                atomicAdd(&hist[((unsigned)e0) >> 24], 1);
                atomicAdd(&hist[((unsigned)e1) >> 24], 1);
                atomicAdd(&hist[((unsigned)e2v) >> 24], 1);
                atomicAdd(&hist[((unsigned)e3) >> 24], 1);
            }
            for (; k < m; ++k) {
                int e = p[k];
                if (base + k < CAPB) raw[base + k] = e;
                atomicAdd(&hist[((unsigned)e) >> 24], 1);
            }
        }
    }
    __syncthreads();
    int total = min(nfill, CAPB);
    // single-wave exclusive scan over 256 node counts (64 lanes * 4)
    if (t < 64) {
        int v[4];
        int s = 0;
        #pragma unroll
        for (int j = 0; j < 4; ++j) { v[j] = s; s += hist[t * 4 + j]; }
        int run = s;
        #pragma unroll
        for (int d = 1; d < 64; d <<= 1) {
            int o = __shfl_up(run, d, 64);
            if (t >= d) run += o;
        }
        int excl = run - s;
        #pragma unroll
        for (int j = 0; j < 4; ++j) {
            int idx = t * 4 + j;
            int p = excl + v[j];
            pref[idx] = p; cursor[idx] = p;
        }
    }
    __syncthreads();
    for (int i = t; i < total; i += 1024) {
        int e = raw[i];
        int p = atomicAdd(&cursor[((unsigned)e) >> 24], 1);
        srt[p] = e;
    }
    __syncthreads();
    int* ep = entries + (size_t)b * cap;
    for (int i = t; i < total; i += 1024) ep[i] = srt[i];
    int node = b * BNODES + t;
    if (t < BNODES && node < n) {
        int deg = hist[t];
        dinv[node]   = rsqrtf((float)deg + 1.0f);   // +1 = self-loop
        rowbeg[node] = b * cap + pref[t];
        rowcnt[node] = deg;
    }
}

// ---------------- GEMM1: h16 = (x @ W1) * dinv; x read direct from global ----------------

__global__ __launch_bounds__(256) void gemm1_kernel(const float* __restrict__ x,
                                                    const float* __restrict__ W,
                                                    const float* __restrict__ dinv,
                                                    __half* __restrict__ h16, int n) {
    __shared__ float Ws[FIN * HID];              // 16 KB
    int t = threadIdx.x;
    for (int i = t; i < FIN * HID; i += 256) Ws[i] = W[i];
    __syncthreads();
    int row0 = blockIdx.x * G1ROWS;
    int tr = t >> 3, tc = t & 7;
    int r0 = row0 + tr * 2, c0 = tc * 4;
    bool v0 = r0 < n, v1 = (r0 + 1) < n;
    const float* p0 = v0 ? &x[(size_t)r0 * FIN] : x;        // safe dummy row
    const float* p1 = v1 ? &x[(size_t)(r0 + 1) * FIN] : x;
    float4 a0 = make_float4(0.f, 0.f, 0.f, 0.f);
    float4 a1 = make_float4(0.f, 0.f, 0.f, 0.f);
    #pragma unroll 8
    for (int k4 = 0; k4 < FIN / 4; ++k4) {
        float4 xv0 = *(const float4*)&p0[k4 * 4];
        float4 xv1 = *(const float4*)&p1[k4 * 4];
        float4 w0 = *(const float4*)&Ws[(k4 * 4 + 0) * HID + c0];
        float4 w1 = *(const float4*)&Ws[(k4 * 4 + 1) * HID + c0];
        float4 w2 = *(const float4*)&Ws[(k4 * 4 + 2) * HID + c0];
        float4 w3 = *(const float4*)&Ws[(k4 * 4 + 3) * HID + c0];
        a0.x = fmaf(xv0.x, w0.x, a0.x); a0.y = fmaf(xv0.x, w0.y, a0.y);
        a0.z = fmaf(xv0.x, w0.z, a0.z); a0.w = fmaf(xv0.x, w0.w, a0.w);
        a0.x = fmaf(xv0.y, w1.x, a0.x); a0.y = fmaf(xv0.y, w1.y, a0.y);
        a0.z = fmaf(xv0.y, w1.z, a0.z); a0.w = fmaf(xv0.y, w1.w, a0.w);
        a0.x = fmaf(xv0.z, w2.x, a0.x); a0.y = fmaf(xv0.z, w2.y, a0.y);
        a0.z = fmaf(xv0.z, w2.z, a0.z); a0.w = fmaf(xv0.z, w2.w, a0.w);
        a0.x = fmaf(xv0.w, w3.x, a0.x); a0.y = fmaf(xv0.w, w3.y, a0.y);
        a0.z = fmaf(xv0.w, w3.z, a0.z); a0.w = fmaf(xv0.w, w3.w, a0.w);
        a1.x = fmaf(xv1.x, w0.x, a1.x); a1.y = fmaf(xv1.x, w0.y, a1.y);
        a1.z = fmaf(xv1.x, w0.z, a1.z); a1.w = fmaf(xv1.x, w0.w, a1.w);
        a1.x = fmaf(xv1.y, w1.x, a1.x); a1.y = fmaf(xv1.y, w1.y, a1.y);
        a1.z = fmaf(xv1.y, w1.z, a1.z); a1.w = fmaf(xv1.y, w1.w, a1.w);
        a1.x = fmaf(xv1.z, w2.x, a1.x); a1.y = fmaf(xv1.z, w2.y, a1.y);
        a1.z = fmaf(xv1.z, w2.z, a1.z); a1.w = fmaf(xv1.z, w2.w, a1.w);
        a1.x = fmaf(xv1.w, w3.x, a1.x); a1.y = fmaf(xv1.w, w3.y, a1.y);
        a1.z = fmaf(xv1.w, w3.z, a1.z); a1.w = fmaf(xv1.w, w3.w, a1.w);
    }
    #pragma unroll
    for (int rr = 0; rr < 2; ++rr) {
        int row = r0 + rr;
        float4 a = rr ? a1 : a0;
        float sc = (row < n) ? dinv[row] : 0.f;
        __half2 q0 = __floats2half2_rn(a.x * sc, a.y * sc);
        __half2 q1 = __floats2half2_rn(a.z * sc, a.w * sc);
        __half2* dstp = (__half2*)&h16[(size_t)row * HID + c0];
        dstp[0] = q0;
        dstp[1] = q1;
    }
}

// ---------------- gather: 4-lane groups, lane owns 8 feats, float4 (16B) loads ----------------
// FUSEW2=1: after relu, apply W2 (32x32) via width-4 shuffles + LDS weights, write h16 for
// layer 2 (pre-scaled by dinv).  FUSEW2=0: write final fp32 output.

template <int FUSEW2>
__global__ __launch_bounds__(256) void gather_kernel(const int* __restrict__ entries,
                                                     const int* __restrict__ rowbeg,
                                                     const int* __restrict__ rowcnt,
                                                     const float* __restrict__ dinv,
                                                     const __half* __restrict__ h16,
                                                     const float* __restrict__ bias,
                                                     const float* __restrict__ W2,
                                                     __half* __restrict__ houth,
                                                     float* __restrict__ outf,
                                                     int n, int sent) {
    __shared__ float Ws[HID * HID];              // 4 KB, FUSEW2 only
    int t = threadIdx.x;
    if (FUSEW2) {
        for (int i = t; i < HID * HID; i += 256) Ws[i] = W2[i];
        __syncthreads();                          // all threads reach this before any return
    }
    int g = t >> 2, f = t & 3;           // 64 nodes/block; lane owns feats [f*8, f*8+8)
    int i = blockIdx.x * 64 + g;
    if (i >= n) return;
    float di = dinv[i];
    float a[8];
    {   // self term: h16 row already carries dinv[i]
        float4 sv4 = *(const float4*)&h16[(size_t)i * HID + f * 8];
        const __half2* sh = (const __half2*)&sv4;
        #pragma unroll
        for (int q = 0; q < 4; ++q) {
            float2 fp = __half22float2(sh[q]);
            a[2 * q] = fp.x; a[2 * q + 1] = fp.y;
        }
    }
    int beg = rowbeg[i], cnt = rowcnt[i];
    for (int base = 0; base < cnt; base += 8) {
        int i0 = base + f, i1 = base + 4 + f;
        int sv0 = (i0 < cnt) ? entries[beg + i0] : sent;   // sentinel = zero row n
        int sv1 = (i1 < cnt) ? entries[beg + i1] : sent;
        sv0 &= 0xFFFFFF; sv1 &= 0xFFFFFF;
        float4 hv[8];
        #pragma unroll
        for (int j = 0; j < 4; ++j) {
            int e = __shfl(sv0, j, 4);
            hv[j] = *(const float4*)&h16[(size_t)e * HID + f * 8];
        }
        #pragma unroll
        for (int j = 0; j < 4; ++j) {
            int e = __shfl(sv1, j, 4);
            hv[4 + j] = *(const float4*)&h16[(size_t)e * HID + f * 8];
        }
        #pragma unroll
        for (int j = 0; j < 8; ++j) {
            const __half2* hp = (const __half2*)&hv[j];
            #pragma unroll
            for (int q = 0; q < 4; ++q) {
                float2 fp = __half22float2(hp[q]);
                a[2 * q] += fp.x; a[2 * q + 1] += fp.y;
            }
        }
    }
    // relu(b + di * a)  -> rl[8]
    float4 b0 = *(const float4*)&bias[f * 8];
    float4 b1 = *(const float4*)&bias[f * 8 + 4];
    float bj[8] = {b0.x, b0.y, b0.z, b0.w, b1.x, b1.y, b1.z, b1.w};
    float rl[8];
    #pragma unroll
    for (int j = 0; j < 8; ++j) rl[j] = fmaxf(bj[j] + di * a[j], 0.f);

    if (!FUSEW2) {
        *(float4*)&outf[(size_t)i * HID + f * 8]     = make_float4(rl[0], rl[1], rl[2], rl[3]);
        *(float4*)&outf[(size_t)i * HID + f * 8 + 4] = make_float4(rl[4], rl[5], rl[6], rl[7]);
    } else {
        // layer-2 GEMM: o[c] = sum_k rl_full[k] * W2[k][c]; 4-lane group holds full row.
        int c0 = f * 8;
        float o[8] = {0.f, 0.f, 0.f, 0.f, 0.f, 0.f, 0.f, 0.f};
        #pragma unroll
        for (int s = 0; s < 4; ++s) {
            #pragma unroll
            for (int j = 0; j < 8; ++j) {
                float av = __shfl(rl[j], s, 4);      // lane s of group owns k = s*8+j
                int k = s * 8 + j;
                float4 w0 = *(const float4*)&Ws[k * HID + c0];
                float4 w1 = *(const float4*)&Ws[k * HID + c0 + 4];
                o[0] = fmaf(av, w0.x, o[0]); o[1] = fmaf(av, w0.y, o[1]);
                o[2] = fmaf(av, w0.z, o[2]); o[3] = fmaf(av, w0.w, o[3]);
                o[4] = fmaf(av, w1.x, o[4]); o[5] = fmaf(av, w1.y, o[5]);
                o[6] = fmaf(av, w1.z, o[6]); o[7] = fmaf(av, w1.w, o[7]);
            }
        }
        float4 tmp;
        __half2* hp2 = (__half2*)&tmp;
        #pragma unroll
        for (int j = 0; j < 4; ++j) hp2[j] = __floats2half2_rn(di * o[2 * j], di * o[2 * j + 1]);
        *(float4*)&houth[(size_t)i * HID + f * 8] = tmp;     // h16 input for layer 2
    }
}

extern "C" void kernel_launch(void* const* d_in, const int* in_sizes, int n_in,
                              void* d_out, int out_size, void* d_ws, size_t ws_size,
                              hipStream_t stream) {
    const float* x  = (const float*)d_in[0];
    const int*   ei = (const int*)d_in[1];
    const float* W1 = (const float*)d_in[2];
    const float* b1 = (const float*)d_in[3];
    const float* W2 = (const float*)d_in[4];
    const float* b2 = (const float*)d_in[5];
    float* out = (float*)d_out;

    int n = in_sizes[0] / FIN;      // 100000
    int E = in_sizes[1] / 2;        // 3200000
    const int* src = ei;
    const int* dst = ei + E;

    int nb = (n + BNODES - 1) / BNODES;          // 391 buckets
    int nchunks = (E + CHUNK - 1) / CHUNK;       // 1563 chunks
    int ggrid = (n + G1ROWS) / G1ROWS;           // covers sentinel row n
    int npad = ggrid * G1ROWS;
    int cap = CAPB;

    char* ws = (char*)d_ws;
    size_t off = 0;
    auto alloc = [&](size_t bytes) { char* p = ws + off; off += (bytes + 255) & ~(size_t)255; return p; };
    int*            ec      = (int*)alloc((size_t)nchunks * CHUNK * 4);         // 12.8 MB
    unsigned short* offt    = (unsigned short*)alloc((size_t)nchunks * (nb + 1) * 2); // 1.2 MB
    int*            entries = (int*)alloc((size_t)nb * cap * 4);                // 14.0 MB
    float*          dinv    = (float*)alloc((size_t)n * 4);
    int*            rowbeg  = (int*)alloc((size_t)n * 4);
    int*            rowcnt  = (int*)alloc((size_t)n * 4);
    __half*         hha     = (__half*)alloc((size_t)npad * HID * 2);           // 6.4 MB (gemm1 out)
    __half*         hhb     = (__half*)alloc((size_t)(n + 1) * HID * 2);        // 6.4 MB (layer2 in)

    // sentinel row n of hhb must be zero (gather reads it for tail lanes)
    hipMemsetAsync(hhb + (size_t)n * HID, 0, HID * 2, stream);

    // ---- preprocessing: DUPLICATED this round (idempotent) to measure CS+BB via dur delta ----
    chunk_sort_kernel<<<nchunks, 256, 0, stream>>>(src, dst, ec, offt, E, nb);
    chunk_sort_kernel<<<nchunks, 256, 0, stream>>>(src, dst, ec, offt, E, nb);
    bucket_build_kernel<<<nb, 1024, 0, stream>>>(ec, offt, entries, dinv, rowbeg, rowcnt,
                                                 n, nb, nchunks, cap);
    bucket_build_kernel<<<nb, 1024, 0, stream>>>(ec, offt, entries, dinv, rowbeg, rowcnt,
                                                 n, nb, nchunks, cap);

    // ---- layer 1: GEMM1 -> gather(+relu) -> fused W2 -> hhb ----
    gemm1_kernel<<<ggrid, 256, 0, stream>>>(x, W1, dinv, hha, n);
    gather_kernel<1><<<(n + 63) / 64, 256, 0, stream>>>(entries, rowbeg, rowcnt, dinv, hha,
                                                        b1, W2, hhb, nullptr, n, n);

    // ---- layer 2: gather(+relu) -> final output ----
    gather_kernel<0><<<(n + 63) / 64, 256, 0, stream>>>(entries, rowbeg, rowcnt, dinv, hhb,
                                                        b2, nullptr, nullptr, out, n, n);
}

// Round 10
// 245.620 us; speedup vs baseline: 1.1371x; 1.1371x over previous
//
#include <hip/hip_runtime.h>
#include <hip/hip_fp16.h>

#define FIN 128
#define HID 32
#define BSHIFT 8                 // 256 nodes per coarse bucket
#define BNODES 256
#define CHUNK 2048               // edges per chunk-sort block
#define NBMAX 512                // max coarse buckets supported in LDS
#define CAPB 8960                // max entries per bucket (mean 8184, +8.6 sigma)
#define G1ROWS 64                // rows per gemm block

// ---------------- A: per-chunk counting sort by bucket (all I/O coalesced) ----------------

__global__ __launch_bounds__(256) void chunk_sort_kernel(const int* __restrict__ src,
                                                         const int* __restrict__ dst,
                                                         int* __restrict__ ec,
                                                         unsigned short* __restrict__ offt,
                                                         int E, int nb) {
    __shared__ int hist[NBMAX];
    __shared__ int pref[NBMAX];
    __shared__ int sorted[CHUNK];
    int c = blockIdx.x, t = threadIdx.x;
    int beg = c * CHUNK;
    int cnt = min(CHUNK, E - beg);
    for (int i = t; i < nb; i += 256) hist[i] = 0;
    __syncthreads();
    int bk[8], ent[8];
    #pragma unroll
    for (int j = 0; j < 8; ++j) {
        int i = t + j * 256;
        if (i < cnt) {
            int d = dst[beg + i];
            bk[j]  = ((unsigned)d) >> BSHIFT;
            ent[j] = src[beg + i] | ((d & (BNODES - 1)) << 24);
            atomicAdd(&hist[bk[j]], 1);
        } else bk[j] = -1;
    }
    __syncthreads();
    // single-wave exclusive scan over nb (<= NBMAX = 64 lanes * 8) buckets
    if (t < 64) {
        int v[8];
        int s = 0;
        #pragma unroll
        for (int j = 0; j < 8; ++j) {
            int idx = t * 8 + j;
            int h = (idx < nb) ? hist[idx] : 0;
            v[j] = s; s += h;
        }
        int run = s;
        #pragma unroll
        for (int d = 1; d < 64; d <<= 1) {
            int o = __shfl_up(run, d, 64);
            if (t >= d) run += o;
        }
        int excl = run - s;
        #pragma unroll
        for (int j = 0; j < 8; ++j) {
            int idx = t * 8 + j;
            if (idx < nb) { int p = excl + v[j]; pref[idx] = p; hist[idx] = p; }
        }
    }
    __syncthreads();
    #pragma unroll
    for (int j = 0; j < 8; ++j) {
        if (bk[j] >= 0) {
            int p = atomicAdd(&hist[bk[j]], 1);
            sorted[p] = ent[j];
        }
    }
    __syncthreads();
    for (int i = t; i < cnt; i += 256) ec[(size_t)c * CHUNK + i] = sorted[i];   // coalesced
    unsigned short* row = offt + (size_t)c * (nb + 1);
    for (int i = t; i < nb; i += 256) row[i] = (unsigned short)pref[i];
    if (t == 0) row[nb] = (unsigned short)cnt;
}

// ---------------- B: per-bucket gather of chunk runs + 512-bin node counting sort ----------------
// bin = local_dst*2 + (src >= half): each node's entries are [srcs<half | srcs>=half].

__global__ __launch_bounds__(1024) void bucket_build_kernel(const int* __restrict__ ec,
                                                            const unsigned short* __restrict__ offt,
                                                            int* __restrict__ entries,
                                                            float* __restrict__ dinv,
                                                            int* __restrict__ rowbeg,
                                                            int* __restrict__ rowmid,
                                                            int* __restrict__ rowcnt,
                                                            int n, int nb, int nchunks, int cap,
                                                            int half) {
    __shared__ int raw[CAPB];
    __shared__ int srt[CAPB];
    __shared__ int hist[2 * BNODES];
    __shared__ int pref[2 * BNODES];
    __shared__ int cursor[2 * BNODES];
    __shared__ int nfill;
    int b = blockIdx.x, t = threadIdx.x;
    for (int i = t; i < 2 * BNODES; i += 1024) hist[i] = 0;
    if (t == 0) nfill = 0;
    __syncthreads();
    for (int c = t; c < nchunks; c += 1024) {
        const unsigned short* row = offt + (size_t)c * (nb + 1);
        int s = row[b], e2 = row[b + 1];
        int m = e2 - s;
        if (m > 0) {
            int base = atomicAdd(&nfill, m);
            const int* p = ec + (size_t)c * CHUNK + s;
            int k = 0;
            for (; k + 4 <= m; k += 4) {           // 4 independent loads in flight
                int e0 = p[k], e1 = p[k + 1], e2v = p[k + 2], e3 = p[k + 3];
                if (base + k + 0 < CAPB) raw[base + k + 0] = e0;
                if (base + k + 1 < CAPB) raw[base + k + 1] = e1;
                if (base + k + 2 < CAPB) raw[base + k + 2] = e2v;
                if (base + k + 3 < CAPB) raw[base + k + 3] = e3;
                atomicAdd(&hist[((((unsigned)e0) >> 24) << 1) | ((e0 & 0xFFFFFF) >= half)], 1);
                atomicAdd(&hist[((((unsigned)e1) >> 24) << 1) | ((e1 & 0xFFFFFF) >= half)], 1);
                atomicAdd(&hist[((((unsigned)e2v) >> 24) << 1) | ((e2v & 0xFFFFFF) >= half)], 1);
                atomicAdd(&hist[((((unsigned)e3) >> 24) << 1) | ((e3 & 0xFFFFFF) >= half)], 1);
            }
            for (; k < m; ++k) {
                int e = p[k];
                if (base + k < CAPB) raw[base + k] = e;
                atomicAdd(&hist[((((unsigned)e) >> 24) << 1) | ((e & 0xFFFFFF) >= half)], 1);
            }
        }
    }
    __syncthreads();
    int total = min(nfill, CAPB);
    // single-wave exclusive scan over 512 bins (64 lanes * 8); hist preserved as counts
    if (t < 64) {
        int v[8];
        int s = 0;
        #pragma unroll
        for (int j = 0; j < 8; ++j) { v[j] = s; s += hist[t * 8 + j]; }
        int run = s;
        #pragma unroll
        for (int d = 1; d < 64; d <<= 1) {
            int o = __shfl_up(run, d, 64);
            if (t >= d) run += o;
        }
        int excl = run - s;
        #pragma unroll
        for (int j = 0; j < 8; ++j) {
            int idx = t * 8 + j;
            int p = excl + v[j];
            pref[idx] = p; cursor[idx] = p;
        }
    }
    __syncthreads();
    for (int i = t; i < total; i += 1024) {
        int e = raw[i];
        int key = ((((unsigned)e) >> 24) << 1) | ((e & 0xFFFFFF) >= half);
        int p = atomicAdd(&cursor[key], 1);
        srt[p] = e;
    }
    __syncthreads();
    int* ep = entries + (size_t)b * cap;
    for (int i = t; i < total; i += 1024) ep[i] = srt[i];
    int node = b * BNODES + t;
    if (t < BNODES && node < n) {
        int d0 = hist[2 * t], d1 = hist[2 * t + 1];
        int deg = d0 + d1;
        dinv[node]   = rsqrtf((float)deg + 1.0f);   // +1 = self-loop
        rowbeg[node] = b * cap + pref[2 * t];
        rowmid[node] = d0;
        rowcnt[node] = deg;
    }
}

// ---------------- GEMM1: h16 = (x @ W1) * dinv; x read direct from global ----------------

__global__ __launch_bounds__(256) void gemm1_kernel(const float* __restrict__ x,
                                                    const float* __restrict__ W,
                                                    const float* __restrict__ dinv,
                                                    __half* __restrict__ h16, int n) {
    __shared__ float Ws[FIN * HID];              // 16 KB
    int t = threadIdx.x;
    for (int i = t; i < FIN * HID; i += 256) Ws[i] = W[i];
    __syncthreads();
    int row0 = blockIdx.x * G1ROWS;
    int tr = t >> 3, tc = t & 7;
    int r0 = row0 + tr * 2, c0 = tc * 4;
    bool v0 = r0 < n, v1 = (r0 + 1) < n;
    const float* p0 = v0 ? &x[(size_t)r0 * FIN] : x;        // safe dummy row
    const float* p1 = v1 ? &x[(size_t)(r0 + 1) * FIN] : x;
    float4 a0 = make_float4(0.f, 0.f, 0.f, 0.f);
    float4 a1 = make_float4(0.f, 0.f, 0.f, 0.f);
    #pragma unroll 8
    for (int k4 = 0; k4 < FIN / 4; ++k4) {
        float4 xv0 = *(const float4*)&p0[k4 * 4];
        float4 xv1 = *(const float4*)&p1[k4 * 4];
        float4 w0 = *(const float4*)&Ws[(k4 * 4 + 0) * HID + c0];
        float4 w1 = *(const float4*)&Ws[(k4 * 4 + 1) * HID + c0];
        float4 w2 = *(const float4*)&Ws[(k4 * 4 + 2) * HID + c0];
        float4 w3 = *(const float4*)&Ws[(k4 * 4 + 3) * HID + c0];
        a0.x = fmaf(xv0.x, w0.x, a0.x); a0.y = fmaf(xv0.x, w0.y, a0.y);
        a0.z = fmaf(xv0.x, w0.z, a0.z); a0.w = fmaf(xv0.x, w0.w, a0.w);
        a0.x = fmaf(xv0.y, w1.x, a0.x); a0.y = fmaf(xv0.y, w1.y, a0.y);
        a0.z = fmaf(xv0.y, w1.z, a0.z); a0.w = fmaf(xv0.y, w1.w, a0.w);
        a0.x = fmaf(xv0.z, w2.x, a0.x); a0.y = fmaf(xv0.z, w2.y, a0.y);
        a0.z = fmaf(xv0.z, w2.z, a0.z); a0.w = fmaf(xv0.z, w2.w, a0.w);
        a0.x = fmaf(xv0.w, w3.x, a0.x); a0.y = fmaf(xv0.w, w3.y, a0.y);
        a0.z = fmaf(xv0.w, w3.z, a0.z); a0.w = fmaf(xv0.w, w3.w, a0.w);
        a1.x = fmaf(xv1.x, w0.x, a1.x); a1.y = fmaf(xv1.x, w0.y, a1.y);
        a1.z = fmaf(xv1.x, w0.z, a1.z); a1.w = fmaf(xv1.x, w0.w, a1.w);
        a1.x = fmaf(xv1.y, w1.x, a1.x); a1.y = fmaf(xv1.y, w1.y, a1.y);
        a1.z = fmaf(xv1.y, w1.z, a1.z); a1.w = fmaf(xv1.y, w1.w, a1.w);
        a1.x = fmaf(xv1.z, w2.x, a1.x); a1.y = fmaf(xv1.z, w2.y, a1.y);
        a1.z = fmaf(xv1.z, w2.z, a1.z); a1.w = fmaf(xv1.z, w2.w, a1.w);
        a1.x = fmaf(xv1.w, w3.x, a1.x); a1.y = fmaf(xv1.w, w3.y, a1.y);
        a1.z = fmaf(xv1.w, w3.z, a1.z); a1.w = fmaf(xv1.w, w3.w, a1.w);
    }
    #pragma unroll
    for (int rr = 0; rr < 2; ++rr) {
        int row = r0 + rr;
        float4 a = rr ? a1 : a0;
        float sc = (row < n) ? dinv[row] : 0.f;      // rows >= n write zeros (sentinel row n)
        __half2 q0 = __floats2half2_rn(a.x * sc, a.y * sc);
        __half2 q1 = __floats2half2_rn(a.z * sc, a.w * sc);
        __half2* dstp = (__half2*)&h16[(size_t)row * HID + c0];
        dstp[0] = q0;
        dstp[1] = q1;
    }
}

// ---------------- gather, src-range split: PASS 0 = srcs<half -> fp32 acc; PASS 1 = finish ----------------
// PASS 1 + FUSEW2=1: apply W2 (32x32) via width-4 shuffles + LDS weights, write h16 for layer 2.
// PASS 1 + FUSEW2=0: write final fp32 output.

template <int PASS, int FUSEW2>
__global__ __launch_bounds__(256) void gather_kernel(const int* __restrict__ entries,
                                                     const int* __restrict__ rowbeg,
                                                     const int* __restrict__ rowmid,
                                                     const int* __restrict__ rowcnt,
                                                     const float* __restrict__ dinv,
                                                     const __half* __restrict__ h16,
                                                     const float* __restrict__ bias,
                                                     const float* __restrict__ W2,
                                                     float* __restrict__ acc,
                                                     __half* __restrict__ houth,
                                                     float* __restrict__ outf,
                                                     int n, int sent) {
    __shared__ float Ws[HID * HID];              // 4 KB, PASS1+FUSEW2 only
    int t = threadIdx.x;
    if (PASS == 1 && FUSEW2) {
        for (int i = t; i < HID * HID; i += 256) Ws[i] = W2[i];
        __syncthreads();                          // all threads reach this before any return
    }
    int g = t >> 2, f = t & 3;           // 64 nodes/block; lane owns feats [f*8, f*8+8)
    int i = blockIdx.x * 64 + g;
    if (i >= n) return;
    float a[8];
    int beg = rowbeg[i];
    int lo, hi;
    if (PASS == 0) {
        lo = 0; hi = rowmid[i];
        #pragma unroll
        for (int j = 0; j < 8; ++j) a[j] = 0.f;
    } else {
        lo = rowmid[i]; hi = rowcnt[i];
        // partial sums from pass A
        float4 pa0 = *(const float4*)&acc[(size_t)i * HID + f * 8];
        float4 pa1 = *(const float4*)&acc[(size_t)i * HID + f * 8 + 4];
        a[0] = pa0.x; a[1] = pa0.y; a[2] = pa0.z; a[3] = pa0.w;
        a[4] = pa1.x; a[5] = pa1.y; a[6] = pa1.z; a[7] = pa1.w;
        // self term: h16 row already carries dinv[i]
        float4 sv4 = *(const float4*)&h16[(size_t)i * HID + f * 8];
        const __half2* sh = (const __half2*)&sv4;
        #pragma unroll
        for (int q = 0; q < 4; ++q) {
            float2 fp = __half22float2(sh[q]);
            a[2 * q] += fp.x; a[2 * q + 1] += fp.y;
        }
    }
    for (int base = lo; base < hi; base += 8) {
        int i0 = base + f, i1 = base + 4 + f;
        int sv0 = (i0 < hi) ? entries[beg + i0] : sent;   // sentinel = zero row n
        int sv1 = (i1 < hi) ? entries[beg + i1] : sent;
        sv0 &= 0xFFFFFF; sv1 &= 0xFFFFFF;
        float4 hv[8];
        #pragma unroll
        for (int j = 0; j < 4; ++j) {
            int e = __shfl(sv0, j, 4);
            hv[j] = *(const float4*)&h16[(size_t)e * HID + f * 8];
        }
        #pragma unroll
        for (int j = 0; j < 4; ++j) {
            int e = __shfl(sv1, j, 4);
            hv[4 + j] = *(const float4*)&h16[(size_t)e * HID + f * 8];
        }
        #pragma unroll
        for (int j = 0; j < 8; ++j) {
            const __half2* hp = (const __half2*)&hv[j];
            #pragma unroll
            for (int q = 0; q < 4; ++q) {
                float2 fp = __half22float2(hp[q]);
                a[2 * q] += fp.x; a[2 * q + 1] += fp.y;
            }
        }
    }
    if (PASS == 0) {
        *(float4*)&acc[(size_t)i * HID + f * 8]     = make_float4(a[0], a[1], a[2], a[3]);
        *(float4*)&acc[(size_t)i * HID + f * 8 + 4] = make_float4(a[4], a[5], a[6], a[7]);
        return;
    }
    // relu(b + di * a)  -> rl[8]
    float di = dinv[i];
    float4 b0 = *(const float4*)&bias[f * 8];
    float4 b1 = *(const float4*)&bias[f * 8 + 4];
    float bj[8] = {b0.x, b0.y, b0.z, b0.w, b1.x, b1.y, b1.z, b1.w};
    float rl[8];
    #pragma unroll
    for (int j = 0; j < 8; ++j) rl[j] = fmaxf(bj[j] + di * a[j], 0.f);

    if (!FUSEW2) {
        *(float4*)&outf[(size_t)i * HID + f * 8]     = make_float4(rl[0], rl[1], rl[2], rl[3]);
        *(float4*)&outf[(size_t)i * HID + f * 8 + 4] = make_float4(rl[4], rl[5], rl[6], rl[7]);
    } else {
        // layer-2 GEMM: o[c] = sum_k rl_full[k] * W2[k][c]; 4-lane group holds full row.
        int c0 = f * 8;
        float o[8] = {0.f, 0.f, 0.f, 0.f, 0.f, 0.f, 0.f, 0.f};
        #pragma unroll
        for (int s = 0; s < 4; ++s) {
            #pragma unroll
            for (int j = 0; j < 8; ++j) {
                float av = __shfl(rl[j], s, 4);      // lane s of group owns k = s*8+j
                int k = s * 8 + j;
                float4 w0 = *(const float4*)&Ws[k * HID + c0];
                float4 w1 = *(const float4*)&Ws[k * HID + c0 + 4];
                o[0] = fmaf(av, w0.x, o[0]); o[1] = fmaf(av, w0.y, o[1]);
                o[2] = fmaf(av, w0.z, o[2]); o[3] = fmaf(av, w0.w, o[3]);
                o[4] = fmaf(av, w1.x, o[4]); o[5] = fmaf(av, w1.y, o[5]);
                o[6] = fmaf(av, w1.z, o[6]); o[7] = fmaf(av, w1.w, o[7]);
            }
        }
        float4 tmp;
        __half2* hp2 = (__half2*)&tmp;
        #pragma unroll
        for (int j = 0; j < 4; ++j) hp2[j] = __floats2half2_rn(di * o[2 * j], di * o[2 * j + 1]);
        *(float4*)&houth[(size_t)i * HID + f * 8] = tmp;     // h16 input for layer 2
    }
}

extern "C" void kernel_launch(void* const* d_in, const int* in_sizes, int n_in,
                              void* d_out, int out_size, void* d_ws, size_t ws_size,
                              hipStream_t stream) {
    const float* x  = (const float*)d_in[0];
    const int*   ei = (const int*)d_in[1];
    const float* W1 = (const float*)d_in[2];
    const float* b1 = (const float*)d_in[3];
    const float* W2 = (const float*)d_in[4];
    const float* b2 = (const float*)d_in[5];
    float* out = (float*)d_out;

    int n = in_sizes[0] / FIN;      // 100000
    int E = in_sizes[1] / 2;        // 3200000
    const int* src = ei;
    const int* dst = ei + E;

    int nb = (n + BNODES - 1) / BNODES;          // 391 buckets
    int nchunks = (E + CHUNK - 1) / CHUNK;       // 1563 chunks
    int ggrid = (n + G1ROWS) / G1ROWS;           // covers sentinel row n
    int npad = ggrid * G1ROWS;
    int cap = CAPB;
    int half = n / 2;                            // src-range split point

    char* ws = (char*)d_ws;
    size_t off = 0;
    auto alloc = [&](size_t bytes) { char* p = ws + off; off += (bytes + 255) & ~(size_t)255; return p; };
    int*            ec      = (int*)alloc((size_t)nchunks * CHUNK * 4);         // 12.8 MB
    unsigned short* offt    = (unsigned short*)alloc((size_t)nchunks * (nb + 1) * 2); // 1.2 MB
    int*            entries = (int*)alloc((size_t)nb * cap * 4);                // 14.0 MB
    float*          dinv    = (float*)alloc((size_t)n * 4);
    int*            rowbeg  = (int*)alloc((size_t)n * 4);
    int*            rowmid  = (int*)alloc((size_t)n * 4);
    int*            rowcnt  = (int*)alloc((size_t)n * 4);
    float*          acc     = (float*)alloc((size_t)n * HID * 4);               // 12.8 MB partials
    __half*         hha     = (__half*)alloc((size_t)npad * HID * 2);           // 6.4 MB (gemm1 out)
    __half*         hhb     = (__half*)alloc((size_t)(n + 1) * HID * 2);        // 6.4 MB (layer2 in)

    // sentinel row n of hhb must be zero (gather reads it for tail lanes)
    hipMemsetAsync(hhb + (size_t)n * HID, 0, HID * 2, stream);

    // ---- preprocessing: chunk sort -> bucket build (512-bin: dst x src-half) ----
    chunk_sort_kernel<<<nchunks, 256, 0, stream>>>(src, dst, ec, offt, E, nb);
    bucket_build_kernel<<<nb, 1024, 0, stream>>>(ec, offt, entries, dinv, rowbeg, rowmid,
                                                 rowcnt, n, nb, nchunks, cap, half);

    int ggath = (n + 63) / 64;
    // ---- layer 1: GEMM1 -> gather A (srcs<half) -> gather B (+self+relu+W2) -> hhb ----
    gemm1_kernel<<<ggrid, 256, 0, stream>>>(x, W1, dinv, hha, n);
    gather_kernel<0, 0><<<ggath, 256, 0, stream>>>(entries, rowbeg, rowmid, rowcnt, dinv, hha,
                                                   nullptr, nullptr, acc, nullptr, nullptr, n, n);
    gather_kernel<1, 1><<<ggath, 256, 0, stream>>>(entries, rowbeg, rowmid, rowcnt, dinv, hha,
                                                   b1, W2, acc, hhb, nullptr, n, n);

    // ---- layer 2: gather A -> gather B -> final output ----
    gather_kernel<0, 0><<<ggath, 256, 0, stream>>>(entries, rowbeg, rowmid, rowcnt, dinv, hhb,
                                                   nullptr, nullptr, acc, nullptr, nullptr, n, n);
    gather_kernel<1, 0><<<ggath, 256, 0, stream>>>(entries, rowbeg, rowmid, rowcnt, dinv, hhb,
                                                   b2, nullptr, acc, nullptr, out, n, n);
}

// Round 11
// 242.835 us; speedup vs baseline: 1.1501x; 1.0115x over previous
//
#include <hip/hip_runtime.h>
#include <hip/hip_fp16.h>

#define FIN 128
#define HID 32
#define BSHIFT 8                 // 256 nodes per coarse bucket
#define BNODES 256
#define CHUNK 2048               // edges per chunk-sort block
#define NBMAX 512                // max coarse buckets supported in LDS
#define CAPB 8960                // max entries per bucket (mean 8184, +8.6 sigma)
#define G1ROWS 64                // rows per gemm block

// ---------------- A: per-chunk counting sort by bucket (all I/O coalesced) ----------------

__global__ __launch_bounds__(256) void chunk_sort_kernel(const int* __restrict__ src,
                                                         const int* __restrict__ dst,
                                                         int* __restrict__ ec,
                                                         unsigned short* __restrict__ offt,
                                                         int E, int nb) {
    __shared__ int hist[NBMAX];
    __shared__ int pref[NBMAX];
    __shared__ int sorted[CHUNK];
    int c = blockIdx.x, t = threadIdx.x;
    int beg = c * CHUNK;
    int cnt = min(CHUNK, E - beg);
    for (int i = t; i < nb; i += 256) hist[i] = 0;
    __syncthreads();
    int bk[8], ent[8];
    #pragma unroll
    for (int j = 0; j < 8; ++j) {
        int i = t + j * 256;
        if (i < cnt) {
            int d = dst[beg + i];
            bk[j]  = ((unsigned)d) >> BSHIFT;
            ent[j] = src[beg + i] | ((d & (BNODES - 1)) << 24);
            atomicAdd(&hist[bk[j]], 1);
        } else bk[j] = -1;
    }
    __syncthreads();
    // single-wave exclusive scan over nb (<= NBMAX = 64 lanes * 8) buckets
    if (t < 64) {
        int v[8];
        int s = 0;
        #pragma unroll
        for (int j = 0; j < 8; ++j) {
            int idx = t * 8 + j;
            int h = (idx < nb) ? hist[idx] : 0;
            v[j] = s; s += h;
        }
        int run = s;
        #pragma unroll
        for (int d = 1; d < 64; d <<= 1) {
            int o = __shfl_up(run, d, 64);
            if (t >= d) run += o;
        }
        int excl = run - s;
        #pragma unroll
        for (int j = 0; j < 8; ++j) {
            int idx = t * 8 + j;
            if (idx < nb) { int p = excl + v[j]; pref[idx] = p; hist[idx] = p; }
        }
    }
    __syncthreads();
    #pragma unroll
    for (int j = 0; j < 8; ++j) {
        if (bk[j] >= 0) {
            int p = atomicAdd(&hist[bk[j]], 1);
            sorted[p] = ent[j];
        }
    }
    __syncthreads();
    for (int i = t; i < cnt; i += 256) ec[(size_t)c * CHUNK + i] = sorted[i];   // coalesced
    unsigned short* row = offt + (size_t)c * (nb + 1);
    for (int i = t; i < nb; i += 256) row[i] = (unsigned short)pref[i];
    if (t == 0) row[nb] = (unsigned short)cnt;
}

// ---------------- B: per-bucket gather of chunk runs + node counting sort ----------------

__global__ __launch_bounds__(1024) void bucket_build_kernel(const int* __restrict__ ec,
                                                            const unsigned short* __restrict__ offt,
                                                            int* __restrict__ entries,
                                                            float* __restrict__ dinv,
                                                            int* __restrict__ rowbeg,
                                                            int* __restrict__ rowcnt,
                                                            int n, int nb, int nchunks, int cap) {
    __shared__ int raw[CAPB];
    __shared__ int srt[CAPB];
    __shared__ int hist[BNODES];
    __shared__ int pref[BNODES];
    __shared__ int cursor[BNODES];
    __shared__ int nfill;
    int b = blockIdx.x, t = threadIdx.x;
    if (t < BNODES) hist[t] = 0;
    if (t == 0) nfill = 0;
    __syncthreads();
    for (int c = t; c < nchunks; c += 1024) {
        const unsigned short* row = offt + (size_t)c * (nb + 1);
        int s = row[b], e2 = row[b + 1];
        int m = e2 - s;
        if (m > 0) {
            int base = atomicAdd(&nfill, m);
            const int* p = ec + (size_t)c * CHUNK + s;
            int k = 0;
            for (; k + 4 <= m; k += 4) {           // 4 independent loads in flight
                int e0 = p[k], e1 = p[k + 1], e2v = p[k + 2], e3 = p[k + 3];
                if (base + k + 0 < CAPB) raw[base + k + 0] = e0;
                if (base + k + 1 < CAPB) raw[base + k + 1] = e1;
                if (base + k + 2 < CAPB) raw[base + k + 2] = e2v;
                if (base + k + 3 < CAPB) raw[base + k + 3] = e3;
                atomicAdd(&hist[((unsigned)e0) >> 24], 1);
                atomicAdd(&hist[((unsigned)e1) >> 24], 1);
                atomicAdd(&hist[((unsigned)e2v) >> 24], 1);
                atomicAdd(&hist[((unsigned)e3) >> 24], 1);
            }
            for (; k < m; ++k) {
                int e = p[k];
                if (base + k < CAPB) raw[base + k] = e;
                atomicAdd(&hist[((unsigned)e) >> 24], 1);
            }
        }
    }
    __syncthreads();
    int total = min(nfill, CAPB);
    // single-wave exclusive scan over 256 node counts (64 lanes * 4)
    if (t < 64) {
        int v[4];
        int s = 0;
        #pragma unroll
        for (int j = 0; j < 4; ++j) { v[j] = s; s += hist[t * 4 + j]; }
        int run = s;
        #pragma unroll
        for (int d = 1; d < 64; d <<= 1) {
            int o = __shfl_up(run, d, 64);
            if (t >= d) run += o;
        }
        int excl = run - s;
        #pragma unroll
        for (int j = 0; j < 4; ++j) {
            int idx = t * 4 + j;
            int p = excl + v[j];
            pref[idx] = p; cursor[idx] = p;
        }
    }
    __syncthreads();
    for (int i = t; i < total; i += 1024) {
        int e = raw[i];
        int p = atomicAdd(&cursor[((unsigned)e) >> 24], 1);
        srt[p] = e;
    }
    __syncthreads();
    int* ep = entries + (size_t)b * cap;
    for (int i = t; i < total; i += 1024) ep[i] = srt[i];
    int node = b * BNODES + t;
    if (t < BNODES && node < n) {
        int deg = hist[t];
        dinv[node]   = rsqrtf((float)deg + 1.0f);   // +1 = self-loop
        rowbeg[node] = b * cap + pref[t];
        rowcnt[node] = deg;
    }
}

// ---------------- GEMM1: h16 = (x @ W1) * dinv; x read direct from global ----------------

__global__ __launch_bounds__(256) void gemm1_kernel(const float* __restrict__ x,
                                                    const float* __restrict__ W,
                                                    const float* __restrict__ dinv,
                                                    __half* __restrict__ h16, int n) {
    __shared__ float Ws[FIN * HID];              // 16 KB
    int t = threadIdx.x;
    for (int i = t; i < FIN * HID; i += 256) Ws[i] = W[i];
    __syncthreads();
    int row0 = blockIdx.x * G1ROWS;
    int tr = t >> 3, tc = t & 7;
    int r0 = row0 + tr * 2, c0 = tc * 4;
    bool v0 = r0 < n, v1 = (r0 + 1) < n;
    const float* p0 = v0 ? &x[(size_t)r0 * FIN] : x;        // safe dummy row
    const float* p1 = v1 ? &x[(size_t)(r0 + 1) * FIN] : x;
    float4 a0 = make_float4(0.f, 0.f, 0.f, 0.f);
    float4 a1 = make_float4(0.f, 0.f, 0.f, 0.f);
    #pragma unroll 8
    for (int k4 = 0; k4 < FIN / 4; ++k4) {
        float4 xv0 = *(const float4*)&p0[k4 * 4];
        float4 xv1 = *(const float4*)&p1[k4 * 4];
        float4 w0 = *(const float4*)&Ws[(k4 * 4 + 0) * HID + c0];
        float4 w1 = *(const float4*)&Ws[(k4 * 4 + 1) * HID + c0];
        float4 w2 = *(const float4*)&Ws[(k4 * 4 + 2) * HID + c0];
        float4 w3 = *(const float4*)&Ws[(k4 * 4 + 3) * HID + c0];
        a0.x = fmaf(xv0.x, w0.x, a0.x); a0.y = fmaf(xv0.x, w0.y, a0.y);
        a0.z = fmaf(xv0.x, w0.z, a0.z); a0.w = fmaf(xv0.x, w0.w, a0.w);
        a0.x = fmaf(xv0.y, w1.x, a0.x); a0.y = fmaf(xv0.y, w1.y, a0.y);
        a0.z = fmaf(xv0.y, w1.z, a0.z); a0.w = fmaf(xv0.y, w1.w, a0.w);
        a0.x = fmaf(xv0.z, w2.x, a0.x); a0.y = fmaf(xv0.z, w2.y, a0.y);
        a0.z = fmaf(xv0.z, w2.z, a0.z); a0.w = fmaf(xv0.z, w2.w, a0.w);
        a0.x = fmaf(xv0.w, w3.x, a0.x); a0.y = fmaf(xv0.w, w3.y, a0.y);
        a0.z = fmaf(xv0.w, w3.z, a0.z); a0.w = fmaf(xv0.w, w3.w, a0.w);
        a1.x = fmaf(xv1.x, w0.x, a1.x); a1.y = fmaf(xv1.x, w0.y, a1.y);
        a1.z = fmaf(xv1.x, w0.z, a1.z); a1.w = fmaf(xv1.x, w0.w, a1.w);
        a1.x = fmaf(xv1.y, w1.x, a1.x); a1.y = fmaf(xv1.y, w1.y, a1.y);
        a1.z = fmaf(xv1.y, w1.z, a1.z); a1.w = fmaf(xv1.y, w1.w, a1.w);
        a1.x = fmaf(xv1.z, w2.x, a1.x); a1.y = fmaf(xv1.z, w2.y, a1.y);
        a1.z = fmaf(xv1.z, w2.z, a1.z); a1.w = fmaf(xv1.z, w2.w, a1.w);
        a1.x = fmaf(xv1.w, w3.x, a1.x); a1.y = fmaf(xv1.w, w3.y, a1.y);
        a1.z = fmaf(xv1.w, w3.z, a1.z); a1.w = fmaf(xv1.w, w3.w, a1.w);
    }
    #pragma unroll
    for (int rr = 0; rr < 2; ++rr) {
        int row = r0 + rr;
        float4 a = rr ? a1 : a0;
        float sc = (row < n) ? dinv[row] : 0.f;      // rows >= n write zeros (sentinel row n)
        __half2 q0 = __floats2half2_rn(a.x * sc, a.y * sc);
        __half2 q1 = __floats2half2_rn(a.z * sc, a.w * sc);
        __half2* dstp = (__half2*)&h16[(size_t)row * HID + c0];
        dstp[0] = q0;
        dstp[1] = q1;
    }
}

// ---------------- gather: 4-lane groups, lane owns 8 feats, float4 (16B) loads ----------------
// FUSEW2=1: after relu, apply W2 (32x32) via width-4 shuffles + LDS weights, write h16 for
// layer 2 (pre-scaled by dinv).  FUSEW2=0: write final fp32 output.

template <int FUSEW2>
__global__ __launch_bounds__(256) void gather_kernel(const int* __restrict__ entries,
                                                     const int* __restrict__ rowbeg,
                                                     const int* __restrict__ rowcnt,
                                                     const float* __restrict__ dinv,
                                                     const __half* __restrict__ h16,
                                                     const float* __restrict__ bias,
                                                     const float* __restrict__ W2,
                                                     __half* __restrict__ houth,
                                                     float* __restrict__ outf,
                                                     int n, int sent) {
    __shared__ float Ws[HID * HID];              // 4 KB, FUSEW2 only
    int t = threadIdx.x;
    if (FUSEW2) {
        for (int i = t; i < HID * HID; i += 256) Ws[i] = W2[i];
        __syncthreads();                          // all threads reach this before any return
    }
    int g = t >> 2, f = t & 3;           // 64 nodes/block; lane owns feats [f*8, f*8+8)
    int i = blockIdx.x * 64 + g;
    if (i >= n) return;
    float di = dinv[i];
    float a[8];
    {   // self term: h16 row already carries dinv[i]
        float4 sv4 = *(const float4*)&h16[(size_t)i * HID + f * 8];
        const __half2* sh = (const __half2*)&sv4;
        #pragma unroll
        for (int q = 0; q < 4; ++q) {
            float2 fp = __half22float2(sh[q]);
            a[2 * q] = fp.x; a[2 * q + 1] = fp.y;
        }
    }
    int beg = rowbeg[i], cnt = rowcnt[i];
    for (int base = 0; base < cnt; base += 8) {
        int i0 = base + f, i1 = base + 4 + f;
        int sv0 = (i0 < cnt) ? entries[beg + i0] : sent;   // sentinel = zero row n
        int sv1 = (i1 < cnt) ? entries[beg + i1] : sent;
        sv0 &= 0xFFFFFF; sv1 &= 0xFFFFFF;
        float4 hv[8];
        #pragma unroll
        for (int j = 0; j < 4; ++j) {
            int e = __shfl(sv0, j, 4);
            hv[j] = *(const float4*)&h16[(size_t)e * HID + f * 8];
        }
        #pragma unroll
        for (int j = 0; j < 4; ++j) {
            int e = __shfl(sv1, j, 4);
            hv[4 + j] = *(const float4*)&h16[(size_t)e * HID + f * 8];
        }
        #pragma unroll
        for (int j = 0; j < 8; ++j) {
            const __half2* hp = (const __half2*)&hv[j];
            #pragma unroll
            for (int q = 0; q < 4; ++q) {
                float2 fp = __half22float2(hp[q]);
                a[2 * q] += fp.x; a[2 * q + 1] += fp.y;
            }
        }
    }
    // relu(b + di * a)  -> rl[8]
    float4 b0 = *(const float4*)&bias[f * 8];
    float4 b1 = *(const float4*)&bias[f * 8 + 4];
    float bj[8] = {b0.x, b0.y, b0.z, b0.w, b1.x, b1.y, b1.z, b1.w};
    float rl[8];
    #pragma unroll
    for (int j = 0; j < 8; ++j) rl[j] = fmaxf(bj[j] + di * a[j], 0.f);

    if (!FUSEW2) {
        *(float4*)&outf[(size_t)i * HID + f * 8]     = make_float4(rl[0], rl[1], rl[2], rl[3]);
        *(float4*)&outf[(size_t)i * HID + f * 8 + 4] = make_float4(rl[4], rl[5], rl[6], rl[7]);
    } else {
        // layer-2 GEMM: o[c] = sum_k rl_full[k] * W2[k][c]; 4-lane group holds full row.
        int c0 = f * 8;
        float o[8] = {0.f, 0.f, 0.f, 0.f, 0.f, 0.f, 0.f, 0.f};
        #pragma unroll
        for (int s = 0; s < 4; ++s) {
            #pragma unroll
            for (int j = 0; j < 8; ++j) {
                float av = __shfl(rl[j], s, 4);      // lane s of group owns k = s*8+j
                int k = s * 8 + j;
                float4 w0 = *(const float4*)&Ws[k * HID + c0];
                float4 w1 = *(const float4*)&Ws[k * HID + c0 + 4];
                o[0] = fmaf(av, w0.x, o[0]); o[1] = fmaf(av, w0.y, o[1]);
                o[2] = fmaf(av, w0.z, o[2]); o[3] = fmaf(av, w0.w, o[3]);
                o[4] = fmaf(av, w1.x, o[4]); o[5] = fmaf(av, w1.y, o[5]);
                o[6] = fmaf(av, w1.z, o[6]); o[7] = fmaf(av, w1.w, o[7]);
            }
        }
        float4 tmp;
        __half2* hp2 = (__half2*)&tmp;
        #pragma unroll
        for (int j = 0; j < 4; ++j) hp2[j] = __floats2half2_rn(di * o[2 * j], di * o[2 * j + 1]);
        *(float4*)&houth[(size_t)i * HID + f * 8] = tmp;     // h16 input for layer 2
    }
}

extern "C" void kernel_launch(void* const* d_in, const int* in_sizes, int n_in,
                              void* d_out, int out_size, void* d_ws, size_t ws_size,
                              hipStream_t stream) {
    const float* x  = (const float*)d_in[0];
    const int*   ei = (const int*)d_in[1];
    const float* W1 = (const float*)d_in[2];
    const float* b1 = (const float*)d_in[3];
    const float* W2 = (const float*)d_in[4];
    const float* b2 = (const float*)d_in[5];
    float* out = (float*)d_out;

    int n = in_sizes[0] / FIN;      // 100000
    int E = in_sizes[1] / 2;        // 3200000
    const int* src = ei;
    const int* dst = ei + E;

    int nb = (n + BNODES - 1) / BNODES;          // 391 buckets
    int nchunks = (E + CHUNK - 1) / CHUNK;       // 1563 chunks
    int ggrid = (n + G1ROWS) / G1ROWS;           // covers sentinel row n
    int npad = ggrid * G1ROWS;
    int cap = CAPB;

    char* ws = (char*)d_ws;
    size_t off = 0;
    auto alloc = [&](size_t bytes) { char* p = ws + off; off += (bytes + 255) & ~(size_t)255; return p; };
    int*            ec      = (int*)alloc((size_t)nchunks * CHUNK * 4);         // 12.8 MB
    unsigned short* offt    = (unsigned short*)alloc((size_t)nchunks * (nb + 1) * 2); // 1.2 MB
    int*            entries = (int*)alloc((size_t)nb * cap * 4);                // 14.0 MB
    float*          dinv    = (float*)alloc((size_t)n * 4);
    int*            rowbeg  = (int*)alloc((size_t)n * 4);
    int*            rowcnt  = (int*)alloc((size_t)n * 4);
    __half*         hha     = (__half*)alloc((size_t)npad * HID * 2);           // 6.4 MB (gemm1 out)
    __half*         hhb     = (__half*)alloc((size_t)(n + 1) * HID * 2);        // 6.4 MB (layer2 in)

    // sentinel row n of hhb must be zero (gather reads it for tail lanes)
    hipMemsetAsync(hhb + (size_t)n * HID, 0, HID * 2, stream);

    // ---- preprocessing: chunk sort (coalesced) -> bucket build (gather) ----
    chunk_sort_kernel<<<nchunks, 256, 0, stream>>>(src, dst, ec, offt, E, nb);
    bucket_build_kernel<<<nb, 1024, 0, stream>>>(ec, offt, entries, dinv, rowbeg, rowcnt,
                                                 n, nb, nchunks, cap);

    // ---- layer 1: GEMM1 -> gather(+relu) -> fused W2 -> hhb ----
    gemm1_kernel<<<ggrid, 256, 0, stream>>>(x, W1, dinv, hha, n);
    gather_kernel<1><<<(n + 63) / 64, 256, 0, stream>>>(entries, rowbeg, rowcnt, dinv, hha,
                                                        b1, W2, hhb, nullptr, n, n);

    // ---- layer 2: gather(+relu) -> final output ----
    gather_kernel<0><<<(n + 63) / 64, 256, 0, stream>>>(entries, rowbeg, rowcnt, dinv, hhb,
                                                        b2, nullptr, nullptr, out, n, n);
}